// Round 9
// baseline (2544.470 us; speedup 1.0000x reference)
//
#include <hip/hip_runtime.h>

// SPINN v9 = v8 + reordered phases: tracking matmul first (all 512 thr),
// tg publish, arrive(B), THEN tree matmul (all 512 thr) fills barrier-B
// latency, wait(B), LSTM, x@W, gates. accR removed (gates sum 8 partials);
// accT aliased onto xS (disjoint lifetimes). Per-set 32-WG monotonic relaxed
// barriers; fence-free sc1 coherence (IC); L1/L2 warm across all steps.

constexpr int NB  = 128;
constexpr int LL  = 32;
constexpr int TT  = 63;
constexpr int NWG = 256;
constexpr int NTH = 512;
constexpr int SROWS = 64;

struct Params {
  const float* seq; const int* trans;
  const float* Wx[4];              // i,o,f,u ; Wx[2]==W_o (ref bug kept)
  const float* Ul[4]; const float* Ur[4];
  const float* bias[4];            // b_i, b_o, b_f, b_u
  const float* tWih; const float* tWhh; const float* tbih; const float* tbhh;
  const float* th0; const float* tc0;
  float* stack; float* tg;
  unsigned* bm;
  float* out;
};

__device__ __forceinline__ float sigm(float x) { return 1.0f / (1.0f + __expf(-x)); }
__device__ __forceinline__ float tanh_f(float x) {
  x = fminf(fmaxf(x, -15.0f), 15.0f);
  float e = __expf(2.0f * x);
  return (e - 1.0f) / (e + 1.0f);
}
__device__ __forceinline__ float cohLoad(const float* a) {
  return __hip_atomic_load(const_cast<float*>(a), __ATOMIC_RELAXED, __HIP_MEMORY_SCOPE_AGENT);
}
__device__ __forceinline__ void cohStore(float* a, float v) {
  __hip_atomic_store(a, v, __ATOMIC_RELAXED, __HIP_MEMORY_SCOPE_AGENT);
}
__device__ __forceinline__ void drainvm() {
  asm volatile("s_waitcnt vmcnt(0)" ::: "memory");
}

// Per-set (32 WG) hierarchical monotonic barrier: 4 sublines x 8 + root x 4.
// blk layout (words): sub0@0 sub1@32 sub2@64 sub3@96 root@128 flag@160
__device__ __forceinline__ void bar_arrive(unsigned* blk, unsigned gen, int l) {
  if (threadIdx.x == 0) {
    unsigned a = __hip_atomic_fetch_add(blk + (l & 3) * 32, 1u, __ATOMIC_RELAXED,
                                        __HIP_MEMORY_SCOPE_AGENT) + 1u;
    if (a == gen * 8u) {
      unsigned r = __hip_atomic_fetch_add(blk + 128, 1u, __ATOMIC_RELAXED,
                                          __HIP_MEMORY_SCOPE_AGENT) + 1u;
      if (r == gen * 4u)
        __hip_atomic_store(blk + 160, gen, __ATOMIC_RELAXED, __HIP_MEMORY_SCOPE_AGENT);
    }
  }
}
__device__ __forceinline__ void bar_wait(unsigned* blk, unsigned gen) {
  if (threadIdx.x == 0) {
    while (__hip_atomic_load(blk + 160, __ATOMIC_RELAXED, __HIP_MEMORY_SCOPE_AGENT) < gen)
      __builtin_amdgcn_s_sleep(1);
  }
  __syncthreads();
}

__launch_bounds__(NTH)
__global__ void spinn_kernel(Params p) {
  const int w = blockIdx.x;
  const int t = threadIdx.x;
  const int cg  = w & 31;            // col-group (XCD = cg%8)
  const int bgp = w >> 5;            // b-group = barrier set
  const int b0  = bgp * 16;
  const int nc0 = cg * 16;
  const int o0  = cg * 8;            // tracking gate-cols [o0, o0+8)

  unsigned* blkA = p.bm + (size_t)bgp * 512;
  unsigned* blkB = blkA + 256;

  __shared__ float opAll[16][1540];  // [b][ buf(512) | sp1h(512) | sp2h(512) ]
  __shared__ float th2s[16][68];
  __shared__ float tc2s[16][68];
  __shared__ float accS[8][64][17];  // tree partials [kth][cc][b]
  __shared__ float xS[64][17];       // x@W; rows 0..31 alias accT[4][8][17]
  __shared__ float tbsum[256];
  __shared__ float biasS[4][16];
  __shared__ unsigned char sp1t[TT + 1][16], sp2t[TT + 1][16];
  __shared__ unsigned char buft[TT + 1][16], redt[TT + 1][16];
  __shared__ int anyredt[TT + 1];
  __shared__ unsigned char qstkS[16][40];

  float (*accT)[8][17] = reinterpret_cast<float (*)[8][17]>(&xS[0][0]);

  // tracking decode (all 512): oth(8) x bl(16) x kth(4)
  const int othT = t & 7, blT = (t >> 3) & 15, kthT = t >> 7;
  const float* wihRow = p.tWih + (size_t)(o0 + othT) * 1536;
  const float* whhRow = p.tWhh + (size_t)(o0 + othT) * 64;

  // ---- prologue
  if (t < 256) tbsum[t] = p.tbih[t] + p.tbhh[t];
  if (t < 64) biasS[t >> 4][t & 15] = p.bias[t >> 4][nc0 + (t & 15)];
  for (int i = t; i < 1024; i += NTH) {
    th2s[i >> 6][i & 63] = p.th0[(size_t)(b0 + (i >> 6)) * 64 + (i & 63)];
    tc2s[i >> 6][i & 63] = p.tc0[(size_t)(b0 + (i >> 6)) * 64 + (i & 63)];
  }
  if (t < 16) {                       // full-schedule sim for our 16 b
    int bl = t, qn = 0, bp = 0;
    for (int s = 1; s <= TT; ++s) {
      int mask = p.trans[(size_t)(b0 + bl) * TT + (s - 1)];
      int s1 = (qn >= 1) ? qstkS[bl][qn - 1] : 0;
      int s2 = (qn >= 2) ? qstkS[bl][qn - 2] : 0;
      int rd = (mask == 1);
      sp1t[s][bl] = (unsigned char)s1;
      sp2t[s][bl] = (unsigned char)s2;
      redt[s][bl] = (unsigned char)rd;
      buft[s][bl] = (unsigned char)((bp < LL) ? bp : LL);
      int qn2 = rd ? (qn - 2) : qn;
      qstkS[bl][qn2] = (unsigned char)s;
      qn = qn2 + 1;
      bp += rd ? 0 : 1;
    }
  }
  __syncthreads();
  if (t == 0) {
    for (int s = 1; s <= TT; ++s) {
      int a = 0;
      for (int bl = 0; bl < 16; ++bl) a |= redt[s][bl];
      anyredt[s] = a;
    }
  }
  // zero our 32-col slice of stack row 0 for our 16 b
  {
    int bl = t >> 5, cc = t & 31;
    int col = (cc < 16) ? (nc0 + cc) : (512 + nc0 + (cc - 16));
    cohStore(p.stack + ((size_t)(b0 + bl) * SROWS) * 1024 + col, 0.0f);
  }
  drainvm();
  __syncthreads();
  unsigned genA = 1, genB = 0;
  bar_arrive(blkA, genA, cg);

  for (int step = 1; step <= TT; ++step) {
    const int anyred = anyredt[step];

    // ---- seq-only staging + seq c-prefetch (no cross-WG dependency)
    #pragma unroll 4
    for (int r = 0; r < 16; ++r) {
      int bx = buft[step][r];
      opAll[r][t] = (bx < LL) ? p.seq[((size_t)(b0 + r) * LL + bx) * 1024 + t] : 0.0f;
    }
    float clv = 0.f, crv = 0.f, bhv = 0.f, bcv = 0.f;
    if (t < 256) {
      const int n = t & 15, bl = t >> 4, na = nc0 + n;
      int bx = buft[step][bl];
      if (bx < LL) {
        bhv = p.seq[((size_t)(b0 + bl) * LL + bx) * 1024 + na];
        bcv = p.seq[((size_t)(b0 + bl) * LL + bx) * 1024 + 512 + na];
      }
    }
    bar_wait(blkA, genA);              // prev-step stack rows now visible

    // ---- stack staging (sc1 from IC) + stack c-prefetch
    #pragma unroll 4
    for (int r = 0; r < 16; ++r) {
      int s1 = sp1t[step][r], s2 = sp2t[step][r];
      float v1 = cohLoad(p.stack + ((size_t)(b0 + r) * SROWS + s1) * 1024 + t);
      float v2 = cohLoad(p.stack + ((size_t)(b0 + r) * SROWS + s2) * 1024 + t);
      opAll[r][512 + t]  = v1;
      opAll[r][1024 + t] = v2;
    }
    if (t < 256) {
      const int n = t & 15, bl = t >> 4, na = nc0 + n;
      clv = cohLoad(p.stack + ((size_t)(b0 + bl) * SROWS + sp1t[step][bl]) * 1024 + 512 + na);
      crv = cohLoad(p.stack + ((size_t)(b0 + bl) * SROWS + sp2t[step][bl]) * 1024 + 512 + na);
    }
    __syncthreads();

    // ---- tracking matmul FIRST (all 512 threads): oth8 x bl16 x kth4, K=400
    {
      const int k0 = kthT * 400;
      float tacc = 0.f;
      #pragma unroll 2
      for (int kf = 0; kf < 100; ++kf) {
        const int k = k0 + kf * 4;
        const float* ws = (k < 1536) ? (wihRow + k) : (whhRow + (k - 1536));
        const float* os = (k < 1536) ? &opAll[blT][k] : &th2s[blT][k - 1536];
        float4 wv = *(const float4*)ws;
        float4 ov = *(const float4*)os;
        tacc += wv.x*ov.x + wv.y*ov.y + wv.z*ov.z + wv.w*ov.w;
      }
      accT[kthT][othT][blT] = tacc;
    }
    __syncthreads();
    if (t < 128) {                        // tg publish: 8 outs x 16 b, sc1
      const int o = t & 7, bl = t >> 3;
      float s = accT[0][o][bl] + accT[1][o][bl] + accT[2][o][bl] + accT[3][o][bl];
      cohStore(p.tg + (size_t)(b0 + bl) * 256 + o0 + o, s);
      drainvm();
    }
    __syncthreads();
    bar_arrive(blkB, ++genB, cg);

    // ---- tree U-matmul fills barrier-B latency (all 512 threads)
    if (anyred) {
      const int bth = t & 3, cth = (t >> 2) & 15, kth = t >> 6;   // 4x16x8
      const int g = cth >> 2;
      const float* Um = (kth < 4) ? p.Ul[g] : p.Ur[g];
      const int koff = (kth & 3) * 128;
      const int nb = nc0 + (cth & 3) * 4;
      const float* w0 = Um + (size_t)(nb    ) * 512 + koff;
      const float* w1 = Um + (size_t)(nb + 1) * 512 + koff;
      const float* w2 = Um + (size_t)(nb + 2) * 512 + koff;
      const float* w3 = Um + (size_t)(nb + 3) * 512 + koff;
      const int ob = ((kth < 4) ? 512 : 1024) + koff;
      float acc[4][4];
      #pragma unroll
      for (int i = 0; i < 4; ++i)
        #pragma unroll
        for (int j = 0; j < 4; ++j) acc[i][j] = 0.0f;
      #pragma unroll 4
      for (int k4 = 0; k4 < 32; ++k4) {
        const int kk = k4 * 4;
        float4 wv0 = *(const float4*)(w0 + kk);
        float4 wv1 = *(const float4*)(w1 + kk);
        float4 wv2 = *(const float4*)(w2 + kk);
        float4 wv3 = *(const float4*)(w3 + kk);
        #pragma unroll
        for (int bi = 0; bi < 4; ++bi) {
          float4 ov = *(const float4*)&opAll[bi * 4 + bth][ob + kk];
          acc[0][bi] += wv0.x*ov.x + wv0.y*ov.y + wv0.z*ov.z + wv0.w*ov.w;
          acc[1][bi] += wv1.x*ov.x + wv1.y*ov.y + wv1.z*ov.z + wv1.w*ov.w;
          acc[2][bi] += wv2.x*ov.x + wv2.y*ov.y + wv2.z*ov.z + wv2.w*ov.w;
          acc[3][bi] += wv3.x*ov.x + wv3.y*ov.y + wv3.z*ov.z + wv3.w*ov.w;
        }
      }
      const int cc0 = cth * 4;
      #pragma unroll
      for (int ci = 0; ci < 4; ++ci)
        #pragma unroll
        for (int bi = 0; bi < 4; ++bi)
          accS[kth][cc0 + ci][bi * 4 + bth] = acc[ci][bi];
    }
    bar_wait(blkB, genB);                 // tg of whole set now visible

    // ---- tracking LSTM elementwise (16 b x 64 j, LDS-local state)
    #pragma unroll
    for (int rep = 0; rep < 2; ++rep) {
      const int it = t + rep * 512;
      const int b = it >> 6, j = it & 63;
      const float* tgb = p.tg + (size_t)(b0 + b) * 256;
      float gi = cohLoad(tgb + j)        + tbsum[j];
      float gf = cohLoad(tgb + 64 + j)   + tbsum[64 + j];
      float gg = cohLoad(tgb + 128 + j)  + tbsum[128 + j];
      float go = cohLoad(tgb + 192 + j)  + tbsum[192 + j];
      float c2 = sigm(gf) * tc2s[b][j] + sigm(gi) * tanh_f(gg);
      float h2 = sigm(go) * tanh_f(c2);
      tc2s[b][j] = c2;
      th2s[b][j] = h2;
    }
    __syncthreads();
    if (anyred) {                         // x@W: 64 cc x 16 b, K=64
      #pragma unroll
      for (int rep = 0; rep < 2; ++rep) {
        const int it = t + rep * 512;
        const int cc = it >> 4, bl = it & 15;
        const float* wr = p.Wx[cc >> 4] + (size_t)(nc0 + (cc & 15)) * 64;
        float x = 0.f;
        #pragma unroll 4
        for (int j4 = 0; j4 < 64; j4 += 4) {
          float4 wv = *(const float4*)(wr + j4);
          float4 xv = *(const float4*)&th2s[bl][j4];
          x += wv.x*xv.x + wv.y*xv.y + wv.z*xv.z + wv.w*xv.w;
        }
        xS[cc][bl] = x;
      }
      __syncthreads();
    }
    // ---- gates + stack row write
    if (t < 256) {
      const int n = t & 15, bl = t >> 4, na = nc0 + n;
      float h, c;
      if (redt[step][bl]) {
        float pre[4];
        #pragma unroll
        for (int g = 0; g < 4; ++g) {
          const int cc = g * 16 + n;
          float s = xS[cc][bl] + biasS[g][n];
          #pragma unroll
          for (int k = 0; k < 8; ++k) s += accS[k][cc][bl];
          pre[g] = s;
        }
        float iv = sigm(pre[0]), ov = sigm(pre[1]);
        float fv = sigm(pre[2]), uv = tanh_f(pre[3]);
        c = iv * uv + fv * (clv + crv);
        h = ov * tanh_f(c);
      } else { h = bhv; c = bcv; }
      float* sr = p.stack + ((size_t)(b0 + bl) * SROWS + step) * 1024;
      cohStore(sr + na, h);
      cohStore(sr + 512 + na, c);
      if (step == TT) p.out[(size_t)(b0 + bl) * 512 + na] = h;
      drainvm();
    }
    __syncthreads();
    bar_arrive(blkA, ++genA, cg);
  }
}

extern "C" void kernel_launch(void* const* d_in, const int* in_sizes, int n_in,
                              void* d_out, int out_size, void* d_ws, size_t ws_size,
                              hipStream_t stream) {
  Params p;
  p.seq   = (const float*)d_in[0];
  p.trans = (const int*)d_in[1];
  p.Wx[0] = (const float*)d_in[2];   // W_i
  p.Wx[1] = (const float*)d_in[4];   // W_o
  p.Wx[2] = (const float*)d_in[4];   // W_o  (ref bug: f-gate uses W_o)
  p.Wx[3] = (const float*)d_in[5];   // W_u
  p.Ul[0] = (const float*)d_in[6];  p.Ur[0] = (const float*)d_in[7];    // i
  p.Ul[1] = (const float*)d_in[10]; p.Ur[1] = (const float*)d_in[11];   // o
  p.Ul[2] = (const float*)d_in[8];  p.Ur[2] = (const float*)d_in[9];    // f
  p.Ul[3] = (const float*)d_in[12]; p.Ur[3] = (const float*)d_in[13];   // u
  p.bias[0] = (const float*)d_in[14];  // b_i
  p.bias[1] = (const float*)d_in[16];  // b_o
  p.bias[2] = (const float*)d_in[15];  // b_f
  p.bias[3] = (const float*)d_in[17];  // b_u
  p.tWih = (const float*)d_in[18];
  p.tWhh = (const float*)d_in[19];
  p.tbih = (const float*)d_in[20];
  p.tbhh = (const float*)d_in[21];
  p.th0  = (const float*)d_in[22];
  p.tc0  = (const float*)d_in[23];

  float* ws = (float*)d_ws;
  size_t off = 0;
  p.stack = ws + off; off += (size_t)NB * SROWS * 1024;  // 33.5 MB
  p.tg    = ws + off; off += (size_t)NB * 256;           // 128 KB
  unsigned* barmem = (unsigned*)(ws + off); off += 4096; // 16 KB
  if (off * sizeof(float) > ws_size) return;
  p.bm  = barmem;
  p.out = (float*)d_out;

  hipMemsetAsync(barmem, 0, 4096 * sizeof(unsigned), stream);

  void* args[] = { &p };
  hipError_t e = hipLaunchCooperativeKernel((void*)spinn_kernel, dim3(NWG), dim3(NTH),
                                            args, 0, stream);
  if (e != hipSuccess) {
    (void)hipGetLastError();
    spinn_kernel<<<dim3(NWG), dim3(NTH), 0, stream>>>(p);
  }
}

// Round 10
// 2251.479 us; speedup vs baseline: 1.1301x; 1.1301x over previous
//
#include <hip/hip_runtime.h>

// SPINN v10 = v8 structure (concurrent tree||tracking, LDS LSTM, per-set
// barriers, arrive/wait split, fence-free sc1 coherence) with halved b-tiles:
// 512 WGs (32 cg x 16 bgp, 8 b-rows each), LDS ~80KB -> 2 WGs/CU. Co-resident
// WGs belong to different barrier sets, so one computes while the other waits.

constexpr int NB  = 128;
constexpr int LL  = 32;
constexpr int TT  = 63;
constexpr int NWG = 512;
constexpr int NTH = 512;
constexpr int SROWS = 64;
constexpr int BPG = 8;             // batch rows per WG

struct Params {
  const float* seq; const int* trans;
  const float* Wx[4];              // i,o,f,u ; Wx[2]==W_o (ref bug kept)
  const float* Ul[4]; const float* Ur[4];
  const float* bias[4];            // b_i, b_o, b_f, b_u
  const float* tWih; const float* tWhh; const float* tbih; const float* tbhh;
  const float* th0; const float* tc0;
  float* stack; float* tg;
  unsigned* bm;
  float* out;
};

__device__ __forceinline__ float sigm(float x) { return 1.0f / (1.0f + __expf(-x)); }
__device__ __forceinline__ float tanh_f(float x) {
  x = fminf(fmaxf(x, -15.0f), 15.0f);
  float e = __expf(2.0f * x);
  return (e - 1.0f) / (e + 1.0f);
}
__device__ __forceinline__ float cohLoad(const float* a) {
  return __hip_atomic_load(const_cast<float*>(a), __ATOMIC_RELAXED, __HIP_MEMORY_SCOPE_AGENT);
}
__device__ __forceinline__ void cohStore(float* a, float v) {
  __hip_atomic_store(a, v, __ATOMIC_RELAXED, __HIP_MEMORY_SCOPE_AGENT);
}
__device__ __forceinline__ void drainvm() {
  asm volatile("s_waitcnt vmcnt(0)" ::: "memory");
}

// Per-set (32 WG) hierarchical monotonic barrier: 4 sublines x 8 + root x 4.
// blk layout (words): sub0@0 sub1@32 sub2@64 sub3@96 root@128 flag@160
__device__ __forceinline__ void bar_arrive(unsigned* blk, unsigned gen, int l) {
  if (threadIdx.x == 0) {
    unsigned a = __hip_atomic_fetch_add(blk + (l & 3) * 32, 1u, __ATOMIC_RELAXED,
                                        __HIP_MEMORY_SCOPE_AGENT) + 1u;
    if (a == gen * 8u) {
      unsigned r = __hip_atomic_fetch_add(blk + 128, 1u, __ATOMIC_RELAXED,
                                          __HIP_MEMORY_SCOPE_AGENT) + 1u;
      if (r == gen * 4u)
        __hip_atomic_store(blk + 160, gen, __ATOMIC_RELAXED, __HIP_MEMORY_SCOPE_AGENT);
    }
  }
}
__device__ __forceinline__ void bar_wait(unsigned* blk, unsigned gen) {
  if (threadIdx.x == 0) {
    while (__hip_atomic_load(blk + 160, __ATOMIC_RELAXED, __HIP_MEMORY_SCOPE_AGENT) < gen)
      __builtin_amdgcn_s_sleep(1);
  }
  __syncthreads();
}

__launch_bounds__(NTH)
__global__ void spinn_kernel(Params p) {
  const int w = blockIdx.x;
  const int t = threadIdx.x;
  const int cg  = w & 31;            // col-group (16 H-cols)
  const int bgp = w >> 5;            // b-group (8 rows) = barrier set
  const int b0  = bgp * BPG;
  const int nc0 = cg * 16;
  const int o0  = cg * 8;            // tracking gate-cols [o0, o0+8)

  unsigned* blkA = p.bm + (size_t)bgp * 1024;
  unsigned* blkB = blkA + 512;

  __shared__ float opAll[BPG][1540]; // [b][ buf(512) | sp1h(512) | sp2h(512) ]
  __shared__ float th2s[BPG][65];
  __shared__ float tc2s[BPG][65];
  __shared__ float accS[8][64][9];   // tree partials [kth][cc][b]
  __shared__ float accT[8][8][9];    // tracking partials [kth][oth][b]
  __shared__ float xS[64][9];
  __shared__ float tbsum[256];
  __shared__ float biasS[4][16];
  __shared__ unsigned char sp1t[TT + 1][BPG], sp2t[TT + 1][BPG];
  __shared__ unsigned char buft[TT + 1][BPG], redt[TT + 1][BPG];
  __shared__ int anyredt[TT + 1];
  __shared__ unsigned char qstkS[BPG][40];

  // tracking decode (t>=256): oth(8) x bth4(4: 2 rows each) x kth(8)
  // tree decode (t<256): bth(2: 4 rows each) x cth(16: 4 cc) x kth(8)

  // ---- prologue
  if (t < 256) tbsum[t] = p.tbih[t] + p.tbhh[t];
  if (t < 64) biasS[t >> 4][t & 15] = p.bias[t >> 4][nc0 + (t & 15)];
  {
    int b = t >> 6, j = t & 63;     // 512 = 8 x 64 exactly
    th2s[b][j] = p.th0[(size_t)(b0 + b) * 64 + j];
    tc2s[b][j] = p.tc0[(size_t)(b0 + b) * 64 + j];
  }
  if (t < BPG) {                     // full-schedule sim for our 8 b
    int bl = t, qn = 0, bp = 0;
    for (int s = 1; s <= TT; ++s) {
      int mask = p.trans[(size_t)(b0 + bl) * TT + (s - 1)];
      int s1 = (qn >= 1) ? qstkS[bl][qn - 1] : 0;
      int s2 = (qn >= 2) ? qstkS[bl][qn - 2] : 0;
      int rd = (mask == 1);
      sp1t[s][bl] = (unsigned char)s1;
      sp2t[s][bl] = (unsigned char)s2;
      redt[s][bl] = (unsigned char)rd;
      buft[s][bl] = (unsigned char)((bp < LL) ? bp : LL);
      int qn2 = rd ? (qn - 2) : qn;
      qstkS[bl][qn2] = (unsigned char)s;
      qn = qn2 + 1;
      bp += rd ? 0 : 1;
    }
  }
  __syncthreads();
  if (t == 0) {
    for (int s = 1; s <= TT; ++s) {
      int a = 0;
      for (int bl = 0; bl < BPG; ++bl) a |= redt[s][bl];
      anyredt[s] = a;
    }
  }
  // zero our 32-col slice of stack row 0 for our 8 b
  if (t < 256) {
    int bl = t >> 5, cc = t & 31;
    int col = (cc < 16) ? (nc0 + cc) : (512 + nc0 + (cc - 16));
    cohStore(p.stack + ((size_t)(b0 + bl) * SROWS) * 1024 + col, 0.0f);
  }
  drainvm();
  __syncthreads();
  unsigned genA = 1, genB = 0;
  bar_arrive(blkA, genA, cg);

  for (int step = 1; step <= TT; ++step) {
    const int anyred = anyredt[step];

    // ---- seq-only staging + seq c-prefetch (no cross-WG dependency)
    #pragma unroll
    for (int r = 0; r < BPG; ++r) {
      int bx = buft[step][r];
      opAll[r][t] = (bx < LL) ? p.seq[((size_t)(b0 + r) * LL + bx) * 1024 + t] : 0.0f;
    }
    float clv = 0.f, crv = 0.f, bhv = 0.f, bcv = 0.f;
    if (t < 128) {
      const int n = t & 15, bl = t >> 4, na = nc0 + n;
      int bx = buft[step][bl];
      if (bx < LL) {
        bhv = p.seq[((size_t)(b0 + bl) * LL + bx) * 1024 + na];
        bcv = p.seq[((size_t)(b0 + bl) * LL + bx) * 1024 + 512 + na];
      }
    }
    bar_wait(blkA, genA);              // prev-step stack rows now visible

    // ---- stack staging (sc1 from IC) + stack c-prefetch
    #pragma unroll
    for (int r = 0; r < BPG; ++r) {
      int s1 = sp1t[step][r], s2 = sp2t[step][r];
      float v1 = cohLoad(p.stack + ((size_t)(b0 + r) * SROWS + s1) * 1024 + t);
      float v2 = cohLoad(p.stack + ((size_t)(b0 + r) * SROWS + s2) * 1024 + t);
      opAll[r][512 + t]  = v1;
      opAll[r][1024 + t] = v2;
    }
    if (t < 128) {
      const int n = t & 15, bl = t >> 4, na = nc0 + n;
      clv = cohLoad(p.stack + ((size_t)(b0 + bl) * SROWS + sp1t[step][bl]) * 1024 + 512 + na);
      crv = cohLoad(p.stack + ((size_t)(b0 + bl) * SROWS + sp2t[step][bl]) * 1024 + 512 + na);
    }
    __syncthreads();

    // ---- compute: tree on t<256 (reduce steps) || tracking on t>=256
    if (t < 256) {
      if (anyred) {
        const int bth = t & 1, cth = (t >> 1) & 15, kth = t >> 5;  // 2x16x8
        const int g = cth >> 2;
        const float* Um = (kth < 4) ? p.Ul[g] : p.Ur[g];
        const int koff = (kth & 3) * 128;
        const int nb = nc0 + (cth & 3) * 4;
        const float* w0 = Um + (size_t)(nb    ) * 512 + koff;
        const float* w1 = Um + (size_t)(nb + 1) * 512 + koff;
        const float* w2 = Um + (size_t)(nb + 2) * 512 + koff;
        const float* w3 = Um + (size_t)(nb + 3) * 512 + koff;
        const int ob = ((kth < 4) ? 512 : 1024) + koff;
        float acc[4][4];
        #pragma unroll
        for (int i = 0; i < 4; ++i)
          #pragma unroll
          for (int j = 0; j < 4; ++j) acc[i][j] = 0.0f;
        #pragma unroll 4
        for (int k4 = 0; k4 < 32; ++k4) {
          const int kk = k4 * 4;
          float4 wv0 = *(const float4*)(w0 + kk);
          float4 wv1 = *(const float4*)(w1 + kk);
          float4 wv2 = *(const float4*)(w2 + kk);
          float4 wv3 = *(const float4*)(w3 + kk);
          #pragma unroll
          for (int bi = 0; bi < 4; ++bi) {
            float4 ov = *(const float4*)&opAll[bth * 4 + bi][ob + kk];
            acc[0][bi] += wv0.x*ov.x + wv0.y*ov.y + wv0.z*ov.z + wv0.w*ov.w;
            acc[1][bi] += wv1.x*ov.x + wv1.y*ov.y + wv1.z*ov.z + wv1.w*ov.w;
            acc[2][bi] += wv2.x*ov.x + wv2.y*ov.y + wv2.z*ov.z + wv2.w*ov.w;
            acc[3][bi] += wv3.x*ov.x + wv3.y*ov.y + wv3.z*ov.z + wv3.w*ov.w;
          }
        }
        const int cc0 = cth * 4;
        #pragma unroll
        for (int ci = 0; ci < 4; ++ci)
          #pragma unroll
          for (int bi = 0; bi < 4; ++bi)
            accS[kth][cc0 + ci][bth * 4 + bi] = acc[ci][bi];
      }
    } else {
      const int tt = t - 256;
      const int oth = tt & 7, bth4 = (tt >> 3) & 3, kth = tt >> 5;  // 8x4x8
      const float* wrow = p.tWih + (size_t)(o0 + oth) * 1536;
      const float* whh  = p.tWhh + (size_t)(o0 + oth) * 64;
      const int k0 = kth * 200;
      const int r0 = bth4 * 2;
      float tacc[2] = {0.f, 0.f};
      #pragma unroll 2
      for (int kf = 0; kf < 50; ++kf) {
        const int k = k0 + kf * 4;
        const float* wsrc = (k < 1536) ? (wrow + k) : (whh + (k - 1536));
        float4 wv = *(const float4*)wsrc;
        #pragma unroll
        for (int ri = 0; ri < 2; ++ri) {
          const int r = r0 + ri;
          const float* os = (k < 1536) ? &opAll[r][k] : &th2s[r][k - 1536];
          float4 ov = *(const float4*)os;
          tacc[ri] += wv.x*ov.x + wv.y*ov.y + wv.z*ov.z + wv.w*ov.w;
        }
      }
      accT[kth][oth][r0]     = tacc[0];
      accT[kth][oth][r0 + 1] = tacc[1];
    }
    __syncthreads();
    if (t < 64) {                        // tg publish: 8 outs x 8 b, sc1
      const int o = t & 7, bl = t >> 3;
      float s = 0.f;
      #pragma unroll
      for (int kt = 0; kt < 8; ++kt) s += accT[kt][o][bl];
      cohStore(p.tg + (size_t)(b0 + bl) * 256 + o0 + o, s);
      drainvm();
    }
    __syncthreads();
    bar_arrive(blkB, ++genB, cg);

    // ---- fill barrier-B latency: nothing heavy needed; x@W weights prefetch
    bar_wait(blkB, genB);                // tg of whole set now visible

    // ---- tracking LSTM elementwise (8 b x 64 j, LDS-local state)
    {
      const int b = t >> 6, j = t & 63;  // 512 = 8 x 64
      const float* tgb = p.tg + (size_t)(b0 + b) * 256;
      float gi = cohLoad(tgb + j)        + tbsum[j];
      float gf = cohLoad(tgb + 64 + j)   + tbsum[64 + j];
      float gg = cohLoad(tgb + 128 + j)  + tbsum[128 + j];
      float go = cohLoad(tgb + 192 + j)  + tbsum[192 + j];
      float c2 = sigm(gf) * tc2s[b][j] + sigm(gi) * tanh_f(gg);
      float h2 = sigm(go) * tanh_f(c2);
      tc2s[b][j] = c2;
      th2s[b][j] = h2;
    }
    __syncthreads();
    if (anyred) {                        // x@W: 64 cc x 8 b, K=64
      const int cc = t >> 3, bl = t & 7; // 512 = 64 x 8
      const float* wr = p.Wx[cc >> 4] + (size_t)(nc0 + (cc & 15)) * 64;
      float x = 0.f;
      #pragma unroll 4
      for (int j4 = 0; j4 < 64; j4 += 4) {
        float4 wv = *(const float4*)(wr + j4);
        float4 xv = *(const float4*)&th2s[bl][j4];
        x += wv.x*xv.x + wv.y*xv.y + wv.z*xv.z + wv.w*xv.w;
      }
      xS[cc][bl] = x;
      __syncthreads();
    }
    // ---- gates + stack row write
    if (t < 128) {
      const int n = t & 15, bl = t >> 4, na = nc0 + n;
      float h, c;
      if (redt[step][bl]) {
        float pre[4];
        #pragma unroll
        for (int g = 0; g < 4; ++g) {
          const int cc = g * 16 + n;
          float s = xS[cc][bl] + biasS[g][n];
          #pragma unroll
          for (int k = 0; k < 8; ++k) s += accS[k][cc][bl];
          pre[g] = s;
        }
        float iv = sigm(pre[0]), ov = sigm(pre[1]);
        float fv = sigm(pre[2]), uv = tanh_f(pre[3]);
        c = iv * uv + fv * (clv + crv);
        h = ov * tanh_f(c);
      } else { h = bhv; c = bcv; }
      float* sr = p.stack + ((size_t)(b0 + bl) * SROWS + step) * 1024;
      cohStore(sr + na, h);
      cohStore(sr + 512 + na, c);
      if (step == TT) p.out[(size_t)(b0 + bl) * 512 + na] = h;
      drainvm();
    }
    __syncthreads();
    bar_arrive(blkA, ++genA, cg);
  }
}

extern "C" void kernel_launch(void* const* d_in, const int* in_sizes, int n_in,
                              void* d_out, int out_size, void* d_ws, size_t ws_size,
                              hipStream_t stream) {
  Params p;
  p.seq   = (const float*)d_in[0];
  p.trans = (const int*)d_in[1];
  p.Wx[0] = (const float*)d_in[2];   // W_i
  p.Wx[1] = (const float*)d_in[4];   // W_o
  p.Wx[2] = (const float*)d_in[4];   // W_o  (ref bug: f-gate uses W_o)
  p.Wx[3] = (const float*)d_in[5];   // W_u
  p.Ul[0] = (const float*)d_in[6];  p.Ur[0] = (const float*)d_in[7];    // i
  p.Ul[1] = (const float*)d_in[10]; p.Ur[1] = (const float*)d_in[11];   // o
  p.Ul[2] = (const float*)d_in[8];  p.Ur[2] = (const float*)d_in[9];    // f
  p.Ul[3] = (const float*)d_in[12]; p.Ur[3] = (const float*)d_in[13];   // u
  p.bias[0] = (const float*)d_in[14];  // b_i
  p.bias[1] = (const float*)d_in[16];  // b_o
  p.bias[2] = (const float*)d_in[15];  // b_f
  p.bias[3] = (const float*)d_in[17];  // b_u
  p.tWih = (const float*)d_in[18];
  p.tWhh = (const float*)d_in[19];
  p.tbih = (const float*)d_in[20];
  p.tbhh = (const float*)d_in[21];
  p.th0  = (const float*)d_in[22];
  p.tc0  = (const float*)d_in[23];

  float* ws = (float*)d_ws;
  size_t off = 0;
  p.stack = ws + off; off += (size_t)NB * SROWS * 1024;    // 33.5 MB
  p.tg    = ws + off; off += (size_t)NB * 256;             // 128 KB
  unsigned* barmem = (unsigned*)(ws + off); off += 16384;  // 64 KB
  if (off * sizeof(float) > ws_size) return;
  p.bm  = barmem;
  p.out = (float*)d_out;

  hipMemsetAsync(barmem, 0, 16384 * sizeof(unsigned), stream);

  void* args[] = { &p };
  hipError_t e = hipLaunchCooperativeKernel((void*)spinn_kernel, dim3(NWG), dim3(NTH),
                                            args, 0, stream);
  if (e != hipSuccess) {
    // plain-launch fallback: per-set barriers are independent, so even at
    // 1 WG/CU residency the sets complete in dispatch order (no deadlock).
    (void)hipGetLastError();
    spinn_kernel<<<dim3(NWG), dim3(NTH), 0, stream>>>(p);
  }
}

// Round 11
// 1175.063 us; speedup vs baseline: 2.1654x; 1.9161x over previous
//
#include <hip/hip_runtime.h>

// SPINN v11 = v8 + early barrier-B arrival: tracking half reduces K in-wave
// (shfl_xor), publishes tg from registers, drains, and each tracking wave
// arrives at B ~2us before the tree half finishes -> wait-B flag already set.
// Also: stack staging loads batched to registers (32 in flight), LSTM tg
// loads issued up-front. Everything else identical to v8 (champion).

constexpr int NB  = 128;
constexpr int LL  = 32;
constexpr int TT  = 63;
constexpr int NWG = 256;
constexpr int NTH = 512;
constexpr int SROWS = 64;

struct Params {
  const float* seq; const int* trans;
  const float* Wx[4];              // i,o,f,u ; Wx[2]==W_o (ref bug kept)
  const float* Ul[4]; const float* Ur[4];
  const float* bias[4];            // b_i, b_o, b_f, b_u
  const float* tWih; const float* tWhh; const float* tbih; const float* tbhh;
  const float* th0; const float* tc0;
  float* stack; float* tg;
  unsigned* bm;
  float* out;
};

__device__ __forceinline__ float sigm(float x) { return 1.0f / (1.0f + __expf(-x)); }
__device__ __forceinline__ float tanh_f(float x) {
  x = fminf(fmaxf(x, -15.0f), 15.0f);
  float e = __expf(2.0f * x);
  return (e - 1.0f) / (e + 1.0f);
}
__device__ __forceinline__ float cohLoad(const float* a) {
  return __hip_atomic_load(const_cast<float*>(a), __ATOMIC_RELAXED, __HIP_MEMORY_SCOPE_AGENT);
}
__device__ __forceinline__ void cohStore(float* a, float v) {
  __hip_atomic_store(a, v, __ATOMIC_RELAXED, __HIP_MEMORY_SCOPE_AGENT);
}
__device__ __forceinline__ void drainvm() {
  asm volatile("s_waitcnt vmcnt(0)" ::: "memory");
}
__device__ __forceinline__ unsigned relAdd(unsigned* a) {
  return __hip_atomic_fetch_add(a, 1u, __ATOMIC_RELAXED, __HIP_MEMORY_SCOPE_AGENT) + 1u;
}

// Barrier A (per-WG arrival): 4 sublines x 8 WGs + root x 4.
// blk layout (words): sub0@0 sub1@32 sub2@64 sub3@96 root@128 flag@160
__device__ __forceinline__ void barA_arrive(unsigned* blk, unsigned gen, int l) {
  if (threadIdx.x == 0) {
    unsigned a = relAdd(blk + (l & 3) * 32);
    if (a == gen * 8u) {
      unsigned r = relAdd(blk + 128);
      if (r == gen * 4u)
        __hip_atomic_store(blk + 160, gen, __ATOMIC_RELAXED, __HIP_MEMORY_SCOPE_AGENT);
    }
  }
}
// Barrier B (per-tracking-WAVE arrival): 4 sublines x 8 WGs x 4 waves + root.
__device__ __forceinline__ void barB_arrive_lane(unsigned* blk, unsigned gen, int l) {
  unsigned a = relAdd(blk + (l & 3) * 32);
  if (a == gen * 32u) {
    unsigned r = relAdd(blk + 128);
    if (r == gen * 4u)
      __hip_atomic_store(blk + 160, gen, __ATOMIC_RELAXED, __HIP_MEMORY_SCOPE_AGENT);
  }
}
__device__ __forceinline__ void bar_wait(unsigned* blk, unsigned gen) {
  if (threadIdx.x == 0) {
    while (__hip_atomic_load(blk + 160, __ATOMIC_RELAXED, __HIP_MEMORY_SCOPE_AGENT) < gen)
      __builtin_amdgcn_s_sleep(1);
  }
  __syncthreads();
}

__launch_bounds__(NTH)
__global__ void spinn_kernel(Params p) {
  const int w = blockIdx.x;
  const int t = threadIdx.x;
  const int cg  = w & 31;            // col-group
  const int bgp = w >> 5;            // b-group = barrier set
  const int b0  = bgp * 16;
  const int nc0 = cg * 16;
  const int o0  = cg * 8;            // tracking gate-cols [o0, o0+8)

  unsigned* blkA = p.bm + (size_t)bgp * 512;
  unsigned* blkB = blkA + 256;

  __shared__ float opAll[16][1540];  // [b][ buf(512) | sp1h(512) | sp2h(512) ]
  __shared__ float th2s[16][68];
  __shared__ float tc2s[16][68];
  __shared__ float accS[4][64][17];  // tree partials [kth][cc][b]
  __shared__ float accR[64][17];     // accS reduced over kth
  __shared__ float xS[64][17];
  __shared__ float tbsum[256];
  __shared__ float biasS[4][16];
  __shared__ unsigned char sp1t[TT + 1][16], sp2t[TT + 1][16];
  __shared__ unsigned char buft[TT + 1][16], redt[TT + 1][16];
  __shared__ int anyredt[TT + 1];
  __shared__ unsigned char qstkS[16][40];

  // ---- prologue
  if (t < 256) tbsum[t] = p.tbih[t] + p.tbhh[t];
  if (t < 64) biasS[t >> 4][t & 15] = p.bias[t >> 4][nc0 + (t & 15)];
  for (int i = t; i < 1024; i += NTH) {
    th2s[i >> 6][i & 63] = p.th0[(size_t)(b0 + (i >> 6)) * 64 + (i & 63)];
    tc2s[i >> 6][i & 63] = p.tc0[(size_t)(b0 + (i >> 6)) * 64 + (i & 63)];
  }
  if (t < 16) {                       // full-schedule sim for our 16 b
    int bl = t, qn = 0, bp = 0;
    for (int s = 1; s <= TT; ++s) {
      int mask = p.trans[(size_t)(b0 + bl) * TT + (s - 1)];
      int s1 = (qn >= 1) ? qstkS[bl][qn - 1] : 0;
      int s2 = (qn >= 2) ? qstkS[bl][qn - 2] : 0;
      int rd = (mask == 1);
      sp1t[s][bl] = (unsigned char)s1;
      sp2t[s][bl] = (unsigned char)s2;
      redt[s][bl] = (unsigned char)rd;
      buft[s][bl] = (unsigned char)((bp < LL) ? bp : LL);
      int qn2 = rd ? (qn - 2) : qn;
      qstkS[bl][qn2] = (unsigned char)s;
      qn = qn2 + 1;
      bp += rd ? 0 : 1;
    }
  }
  __syncthreads();
  if (t == 0) {
    for (int s = 1; s <= TT; ++s) {
      int a = 0;
      for (int bl = 0; bl < 16; ++bl) a |= redt[s][bl];
      anyredt[s] = a;
    }
  }
  // zero our 32-col slice of stack row 0 for our 16 b
  {
    int bl = t >> 5, cc = t & 31;
    int col = (cc < 16) ? (nc0 + cc) : (512 + nc0 + (cc - 16));
    cohStore(p.stack + ((size_t)(b0 + bl) * SROWS) * 1024 + col, 0.0f);
  }
  drainvm();
  __syncthreads();
  unsigned genA = 1, genB = 0;
  barA_arrive(blkA, genA, cg);

  for (int step = 1; step <= TT; ++step) {
    const int anyred = anyredt[step];
    const unsigned gB = ++genB;

    // ---- seq-only staging + seq c-prefetch (no cross-WG dependency)
    #pragma unroll 4
    for (int r = 0; r < 16; ++r) {
      int bx = buft[step][r];
      opAll[r][t] = (bx < LL) ? p.seq[((size_t)(b0 + r) * LL + bx) * 1024 + t] : 0.0f;
    }
    float clv = 0.f, crv = 0.f, bhv = 0.f, bcv = 0.f;
    if (t < 256) {
      const int n = t & 15, bl = t >> 4, na = nc0 + n;
      int bx = buft[step][bl];
      if (bx < LL) {
        bhv = p.seq[((size_t)(b0 + bl) * LL + bx) * 1024 + na];
        bcv = p.seq[((size_t)(b0 + bl) * LL + bx) * 1024 + 512 + na];
      }
    }
    bar_wait(blkA, genA);              // prev-step stack rows now visible

    // ---- stack staging: batch all 32 coherent loads into regs, then LDS
    {
      float v1r[16], v2r[16];
      #pragma unroll
      for (int r = 0; r < 16; ++r) {
        v1r[r] = cohLoad(p.stack + ((size_t)(b0 + r) * SROWS + sp1t[step][r]) * 1024 + t);
        v2r[r] = cohLoad(p.stack + ((size_t)(b0 + r) * SROWS + sp2t[step][r]) * 1024 + t);
      }
      #pragma unroll
      for (int r = 0; r < 16; ++r) {
        opAll[r][512 + t]  = v1r[r];
        opAll[r][1024 + t] = v2r[r];
      }
    }
    if (t < 256) {
      const int n = t & 15, bl = t >> 4, na = nc0 + n;
      clv = cohLoad(p.stack + ((size_t)(b0 + bl) * SROWS + sp1t[step][bl]) * 1024 + 512 + na);
      crv = cohLoad(p.stack + ((size_t)(b0 + bl) * SROWS + sp2t[step][bl]) * 1024 + 512 + na);
    }
    __syncthreads();

    // ---- compute: tree on t<256 || tracking on t>=256 (self-contained)
    if (t < 256) {
      if (anyred) {
        const int bth = t & 3, cth = (t >> 2) & 15, kth = t >> 6;   // 4x16x4
        const int g = cth >> 2;
        const float* Um = (kth < 2) ? p.Ul[g] : p.Ur[g];
        const int koff = (kth & 1) * 256;
        const int nb = nc0 + (cth & 3) * 4;
        const float* w0 = Um + (size_t)(nb    ) * 512 + koff;
        const float* w1 = Um + (size_t)(nb + 1) * 512 + koff;
        const float* w2 = Um + (size_t)(nb + 2) * 512 + koff;
        const float* w3 = Um + (size_t)(nb + 3) * 512 + koff;
        const int ob = ((kth < 2) ? 512 : 1024) + koff;
        float acc[4][4];
        #pragma unroll
        for (int i = 0; i < 4; ++i)
          #pragma unroll
          for (int j = 0; j < 4; ++j) acc[i][j] = 0.0f;
        #pragma unroll 2
        for (int k4 = 0; k4 < 64; ++k4) {
          const int kk = k4 * 4;
          float4 wv0 = *(const float4*)(w0 + kk);
          float4 wv1 = *(const float4*)(w1 + kk);
          float4 wv2 = *(const float4*)(w2 + kk);
          float4 wv3 = *(const float4*)(w3 + kk);
          #pragma unroll
          for (int bi = 0; bi < 4; ++bi) {
            float4 ov = *(const float4*)&opAll[bi * 4 + bth][ob + kk];
            acc[0][bi] += wv0.x*ov.x + wv0.y*ov.y + wv0.z*ov.z + wv0.w*ov.w;
            acc[1][bi] += wv1.x*ov.x + wv1.y*ov.y + wv1.z*ov.z + wv1.w*ov.w;
            acc[2][bi] += wv2.x*ov.x + wv2.y*ov.y + wv2.z*ov.z + wv2.w*ov.w;
            acc[3][bi] += wv3.x*ov.x + wv3.y*ov.y + wv3.z*ov.z + wv3.w*ov.w;
          }
        }
        const int cc0 = cth * 4;
        #pragma unroll
        for (int ci = 0; ci < 4; ++ci)
          #pragma unroll
          for (int bi = 0; bi < 4; ++bi)
            accS[kth][cc0 + ci][bi * 4 + bth] = acc[ci][bi];
      }
    } else {
      // tracking: wave q (rows q*4..q*4+3), lane = o*8 + kth; K=200 per kth
      const int tt = t - 256;
      const int q = tt >> 6;               // wave 0..3
      const int lane = tt & 63;
      const int o = lane >> 3, kth = lane & 7;
      const int r0 = q * 4;
      const float* wrow = p.tWih + (size_t)(o0 + o) * 1536;
      const float* whh  = p.tWhh + (size_t)(o0 + o) * 64;
      const int k0 = kth * 200;
      float tacc[4] = {0.f, 0.f, 0.f, 0.f};
      #pragma unroll 2
      for (int kf = 0; kf < 50; ++kf) {
        const int k = k0 + kf * 4;
        const float* wsrc = (k < 1536) ? (wrow + k) : (whh + (k - 1536));
        float4 wv = *(const float4*)wsrc;
        #pragma unroll
        for (int ri = 0; ri < 4; ++ri) {
          const int r = r0 + ri;
          const float* os = (k < 1536) ? &opAll[r][k] : &th2s[r][k - 1536];
          float4 ov = *(const float4*)os;
          tacc[ri] += wv.x*ov.x + wv.y*ov.y + wv.z*ov.z + wv.w*ov.w;
        }
      }
      // in-wave 8-way reduction over kth (aligned 8-lane groups)
      #pragma unroll
      for (int ri = 0; ri < 4; ++ri) {
        float v = tacc[ri];
        v += __shfl_xor(v, 1);
        v += __shfl_xor(v, 2);
        v += __shfl_xor(v, 4);
        tacc[ri] = v;
      }
      if (kth == 0) {
        #pragma unroll
        for (int ri = 0; ri < 4; ++ri)
          cohStore(p.tg + (size_t)(b0 + r0 + ri) * 256 + o0 + o, tacc[ri]);
      }
      drainvm();                           // wave-level: drains the tg stores
      if (lane == 0) barB_arrive_lane(blkB, gB, cg);   // EARLY arrival
    }
    __syncthreads();

    // ---- fill barrier-B latency: reduce accS over kth
    if (anyred) {
      #pragma unroll
      for (int rep = 0; rep < 2; ++rep) {
        const int it = t + rep * 512;
        const int cc = it >> 4, bl = it & 15;
        accR[cc][bl] = accS[0][cc][bl] + accS[1][cc][bl]
                     + accS[2][cc][bl] + accS[3][cc][bl];
      }
    }
    bar_wait(blkB, gB);                   // tg of whole set now visible

    // ---- tracking LSTM elementwise (16 b x 64 j; 8 tg loads up-front)
    {
      float gi[2], gf[2], gg[2], go[2];
      int bbp[2], jjp[2];
      #pragma unroll
      for (int rep = 0; rep < 2; ++rep) {
        const int it = t + rep * 512;
        bbp[rep] = it >> 6; jjp[rep] = it & 63;
        const float* tgb = p.tg + (size_t)(b0 + bbp[rep]) * 256;
        gi[rep] = cohLoad(tgb + jjp[rep]);
        gf[rep] = cohLoad(tgb + 64 + jjp[rep]);
        gg[rep] = cohLoad(tgb + 128 + jjp[rep]);
        go[rep] = cohLoad(tgb + 192 + jjp[rep]);
      }
      #pragma unroll
      for (int rep = 0; rep < 2; ++rep) {
        const int b = bbp[rep], j = jjp[rep];
        float c2 = sigm(gf[rep] + tbsum[64 + j]) * tc2s[b][j]
                 + sigm(gi[rep] + tbsum[j]) * tanh_f(gg[rep] + tbsum[128 + j]);
        float h2 = sigm(go[rep] + tbsum[192 + j]) * tanh_f(c2);
        tc2s[b][j] = c2;
        th2s[b][j] = h2;
      }
    }
    __syncthreads();
    if (anyred) {                         // x@W: 64 cc x 16 b, K=64
      #pragma unroll
      for (int rep = 0; rep < 2; ++rep) {
        const int it = t + rep * 512;
        const int cc = it >> 4, bl = it & 15;
        const float* wr = p.Wx[cc >> 4] + (size_t)(nc0 + (cc & 15)) * 64;
        float x = 0.f;
        #pragma unroll 4
        for (int j4 = 0; j4 < 64; j4 += 4) {
          float4 wv = *(const float4*)(wr + j4);
          float4 xv = *(const float4*)&th2s[bl][j4];
          x += wv.x*xv.x + wv.y*xv.y + wv.z*xv.z + wv.w*xv.w;
        }
        xS[cc][bl] = x;
      }
      __syncthreads();
    }
    // ---- gates + stack row write
    if (t < 256) {
      const int n = t & 15, bl = t >> 4, na = nc0 + n;
      float h, c;
      if (redt[step][bl]) {
        float pre[4];
        #pragma unroll
        for (int g = 0; g < 4; ++g) {
          const int cc = g * 16 + n;
          pre[g] = accR[cc][bl] + xS[cc][bl] + biasS[g][n];
        }
        float iv = sigm(pre[0]), ov = sigm(pre[1]);
        float fv = sigm(pre[2]), uv = tanh_f(pre[3]);
        c = iv * uv + fv * (clv + crv);
        h = ov * tanh_f(c);
      } else { h = bhv; c = bcv; }
      float* sr = p.stack + ((size_t)(b0 + bl) * SROWS + step) * 1024;
      cohStore(sr + na, h);
      cohStore(sr + 512 + na, c);
      if (step == TT) p.out[(size_t)(b0 + bl) * 512 + na] = h;
      drainvm();
    }
    __syncthreads();
    barA_arrive(blkA, ++genA, cg);
  }
}

extern "C" void kernel_launch(void* const* d_in, const int* in_sizes, int n_in,
                              void* d_out, int out_size, void* d_ws, size_t ws_size,
                              hipStream_t stream) {
  Params p;
  p.seq   = (const float*)d_in[0];
  p.trans = (const int*)d_in[1];
  p.Wx[0] = (const float*)d_in[2];   // W_i
  p.Wx[1] = (const float*)d_in[4];   // W_o
  p.Wx[2] = (const float*)d_in[4];   // W_o  (ref bug: f-gate uses W_o)
  p.Wx[3] = (const float*)d_in[5];   // W_u
  p.Ul[0] = (const float*)d_in[6];  p.Ur[0] = (const float*)d_in[7];    // i
  p.Ul[1] = (const float*)d_in[10]; p.Ur[1] = (const float*)d_in[11];   // o
  p.Ul[2] = (const float*)d_in[8];  p.Ur[2] = (const float*)d_in[9];    // f
  p.Ul[3] = (const float*)d_in[12]; p.Ur[3] = (const float*)d_in[13];   // u
  p.bias[0] = (const float*)d_in[14];  // b_i
  p.bias[1] = (const float*)d_in[16];  // b_o
  p.bias[2] = (const float*)d_in[15];  // b_f
  p.bias[3] = (const float*)d_in[17];  // b_u
  p.tWih = (const float*)d_in[18];
  p.tWhh = (const float*)d_in[19];
  p.tbih = (const float*)d_in[20];
  p.tbhh = (const float*)d_in[21];
  p.th0  = (const float*)d_in[22];
  p.tc0  = (const float*)d_in[23];

  float* ws = (float*)d_ws;
  size_t off = 0;
  p.stack = ws + off; off += (size_t)NB * SROWS * 1024;  // 33.5 MB
  p.tg    = ws + off; off += (size_t)NB * 256;           // 128 KB
  unsigned* barmem = (unsigned*)(ws + off); off += 4096; // 16 KB
  if (off * sizeof(float) > ws_size) return;
  p.bm  = barmem;
  p.out = (float*)d_out;

  hipMemsetAsync(barmem, 0, 4096 * sizeof(unsigned), stream);

  void* args[] = { &p };
  hipError_t e = hipLaunchCooperativeKernel((void*)spinn_kernel, dim3(NWG), dim3(NTH),
                                            args, 0, stream);
  if (e != hipSuccess) {
    (void)hipGetLastError();
    spinn_kernel<<<dim3(NWG), dim3(NTH), 0, stream>>>(p);
  }
}

// Round 12
// 1055.576 us; speedup vs baseline: 2.4105x; 1.1132x over previous
//
#include <hip/hip_runtime.h>

// SPINN v12 = v11 + (1) vectorized coherent staging (64-bit agent-atomic
// loads -> float4, b128 LDS writes), (2) seq staging skipped when buffer
// pointer unchanged (shift steps s>=4), (3) early barrier-A arrival on shift
// steps (stack row = buf row, written pre-wait; tracking/LSTM tail overlaps
// other WGs' next step). Structure otherwise identical to v11 (champion).

constexpr int NB  = 128;
constexpr int LL  = 32;
constexpr int TT  = 63;
constexpr int NWG = 256;
constexpr int NTH = 512;
constexpr int SROWS = 64;

struct Params {
  const float* seq; const int* trans;
  const float* Wx[4];              // i,o,f,u ; Wx[2]==W_o (ref bug kept)
  const float* Ul[4]; const float* Ur[4];
  const float* bias[4];            // b_i, b_o, b_f, b_u
  const float* tWih; const float* tWhh; const float* tbih; const float* tbhh;
  const float* th0; const float* tc0;
  float* stack; float* tg;
  unsigned* bm;
  float* out;
};

__device__ __forceinline__ float sigm(float x) { return 1.0f / (1.0f + __expf(-x)); }
__device__ __forceinline__ float tanh_f(float x) {
  x = fminf(fmaxf(x, -15.0f), 15.0f);
  float e = __expf(2.0f * x);
  return (e - 1.0f) / (e + 1.0f);
}
__device__ __forceinline__ float cohLoad(const float* a) {
  return __hip_atomic_load(const_cast<float*>(a), __ATOMIC_RELAXED, __HIP_MEMORY_SCOPE_AGENT);
}
// coherence (not atomicity) is what we need: 2x native 64-bit agent loads
__device__ __forceinline__ float4 cohLoad4(const float* a) {
  union { unsigned long long u[2]; float4 f; } r;
  const unsigned long long* p64 = (const unsigned long long*)a;
  r.u[0] = __hip_atomic_load(const_cast<unsigned long long*>(p64),
                             __ATOMIC_RELAXED, __HIP_MEMORY_SCOPE_AGENT);
  r.u[1] = __hip_atomic_load(const_cast<unsigned long long*>(p64 + 1),
                             __ATOMIC_RELAXED, __HIP_MEMORY_SCOPE_AGENT);
  return r.f;
}
__device__ __forceinline__ void cohStore(float* a, float v) {
  __hip_atomic_store(a, v, __ATOMIC_RELAXED, __HIP_MEMORY_SCOPE_AGENT);
}
__device__ __forceinline__ void cohStore2(float* a, float2 v) {
  union { float2 f; unsigned long long u; } r; r.f = v;
  __hip_atomic_store((unsigned long long*)a, r.u, __ATOMIC_RELAXED,
                     __HIP_MEMORY_SCOPE_AGENT);
}
__device__ __forceinline__ void drainvm() {
  asm volatile("s_waitcnt vmcnt(0)" ::: "memory");
}
__device__ __forceinline__ unsigned relAdd(unsigned* a) {
  return __hip_atomic_fetch_add(a, 1u, __ATOMIC_RELAXED, __HIP_MEMORY_SCOPE_AGENT) + 1u;
}

// Barrier A (per-WG arrival): 4 sublines x 8 WGs + root x 4.
__device__ __forceinline__ void barA_arrive(unsigned* blk, unsigned gen, int l) {
  if (threadIdx.x == 0) {
    unsigned a = relAdd(blk + (l & 3) * 32);
    if (a == gen * 8u) {
      unsigned r = relAdd(blk + 128);
      if (r == gen * 4u)
        __hip_atomic_store(blk + 160, gen, __ATOMIC_RELAXED, __HIP_MEMORY_SCOPE_AGENT);
    }
  }
}
// Barrier B (per-tracking-WAVE arrival): 4 sublines x 8 WGs x 4 waves + root.
__device__ __forceinline__ void barB_arrive_lane(unsigned* blk, unsigned gen, int l) {
  unsigned a = relAdd(blk + (l & 3) * 32);
  if (a == gen * 32u) {
    unsigned r = relAdd(blk + 128);
    if (r == gen * 4u)
      __hip_atomic_store(blk + 160, gen, __ATOMIC_RELAXED, __HIP_MEMORY_SCOPE_AGENT);
  }
}
__device__ __forceinline__ void bar_wait(unsigned* blk, unsigned gen) {
  if (threadIdx.x == 0) {
    while (__hip_atomic_load(blk + 160, __ATOMIC_RELAXED, __HIP_MEMORY_SCOPE_AGENT) < gen)
      __builtin_amdgcn_s_sleep(1);
  }
  __syncthreads();
}

__launch_bounds__(NTH)
__global__ void spinn_kernel(Params p) {
  const int w = blockIdx.x;
  const int t = threadIdx.x;
  const int cg  = w & 31;
  const int bgp = w >> 5;
  const int b0  = bgp * 16;
  const int nc0 = cg * 16;
  const int o0  = cg * 8;

  unsigned* blkA = p.bm + (size_t)bgp * 512;
  unsigned* blkB = blkA + 256;

  __shared__ float opAll[16][1540];
  __shared__ float th2s[16][68];
  __shared__ float tc2s[16][68];
  __shared__ float accS[4][64][17];
  __shared__ float accR[64][17];
  __shared__ float xS[64][17];
  __shared__ float tbsum[256];
  __shared__ float biasS[4][16];
  __shared__ unsigned char sp1t[TT + 1][16], sp2t[TT + 1][16];
  __shared__ unsigned char buft[TT + 1][16], redt[TT + 1][16];
  __shared__ int anyredt[TT + 1];
  __shared__ int bufSamet[TT + 1];
  __shared__ unsigned char qstkS[16][40];

  const int rq = t >> 7;            // 0..3 (row quarter for staging)
  const int kb = (t & 127) * 4;     // float4 K offset 0..508

  // ---- prologue
  if (t < 256) tbsum[t] = p.tbih[t] + p.tbhh[t];
  if (t < 64) biasS[t >> 4][t & 15] = p.bias[t >> 4][nc0 + (t & 15)];
  for (int i = t; i < 1024; i += NTH) {
    th2s[i >> 6][i & 63] = p.th0[(size_t)(b0 + (i >> 6)) * 64 + (i & 63)];
    tc2s[i >> 6][i & 63] = p.tc0[(size_t)(b0 + (i >> 6)) * 64 + (i & 63)];
  }
  if (t < 16) {
    buft[0][t] = 255;
    int bl = t, qn = 0, bp = 0;
    for (int s = 1; s <= TT; ++s) {
      int mask = p.trans[(size_t)(b0 + bl) * TT + (s - 1)];
      int s1 = (qn >= 1) ? qstkS[bl][qn - 1] : 0;
      int s2 = (qn >= 2) ? qstkS[bl][qn - 2] : 0;
      int rd = (mask == 1);
      sp1t[s][bl] = (unsigned char)s1;
      sp2t[s][bl] = (unsigned char)s2;
      redt[s][bl] = (unsigned char)rd;
      buft[s][bl] = (unsigned char)((bp < LL) ? bp : LL);
      int qn2 = rd ? (qn - 2) : qn;
      qstkS[bl][qn2] = (unsigned char)s;
      qn = qn2 + 1;
      bp += rd ? 0 : 1;
    }
  }
  __syncthreads();
  if (t == 0) {
    for (int s = 1; s <= TT; ++s) {
      int a = 0, same = 1;
      for (int bl = 0; bl < 16; ++bl) {
        a |= redt[s][bl];
        same &= (buft[s][bl] == buft[s - 1][bl]);
      }
      anyredt[s] = a;
      bufSamet[s] = same;
    }
  }
  // zero our 32-col slice of stack row 0 for our 16 b
  {
    int bl = t >> 5, cc = t & 31;
    int col = (cc < 16) ? (nc0 + cc) : (512 + nc0 + (cc - 16));
    cohStore(p.stack + ((size_t)(b0 + bl) * SROWS) * 1024 + col, 0.0f);
  }
  drainvm();
  __syncthreads();
  unsigned genA = 1, genB = 0;
  barA_arrive(blkA, genA, cg);

  for (int step = 1; step <= TT; ++step) {
    const int anyred = anyredt[step];
    const unsigned gB = ++genB;
    const unsigned gAw = genA, gAn = genA + 1;

    // ---- pre-wait: seq staging (only if buf changed), float4 loads
    if (!bufSamet[step]) {
      #pragma unroll
      for (int i = 0; i < 4; ++i) {
        const int r = i * 4 + rq;
        const int bx = buft[step][r];
        float4 v = make_float4(0.f, 0.f, 0.f, 0.f);
        if (bx < LL) v = *(const float4*)(p.seq + ((size_t)(b0 + r) * LL + bx) * 1024 + kb);
        *(float4*)&opAll[r][kb] = v;
      }
    }
    // ---- pre-wait: shift steps write stack row from seq directly
    if (!anyred && t < 128) {
      const int bl = t >> 3, nf = (t & 7) * 2, na = nc0 + nf;
      const int bx = buft[step][bl];
      float2 h2 = make_float2(0.f, 0.f), c2 = make_float2(0.f, 0.f);
      if (bx < LL) {
        const float* sb = p.seq + ((size_t)(b0 + bl) * LL + bx) * 1024;
        h2 = *(const float2*)(sb + na);
        c2 = *(const float2*)(sb + 512 + na);
      }
      float* sr = p.stack + ((size_t)(b0 + bl) * SROWS + step) * 1024;
      cohStore2(sr + na, h2);
      cohStore2(sr + 512 + na, c2);
    }
    float bhv = 0.f, bcv = 0.f, clv = 0.f, crv = 0.f;
    if (anyred && t < 256) {            // fallback values for mixed rows
      const int n = t & 15, bl = t >> 4, na = nc0 + n;
      int bx = buft[step][bl];
      if (bx < LL) {
        bhv = p.seq[((size_t)(b0 + bl) * LL + bx) * 1024 + na];
        bcv = p.seq[((size_t)(b0 + bl) * LL + bx) * 1024 + 512 + na];
      }
    }
    bar_wait(blkA, gAw);               // prev-step stack rows now visible

    // ---- stack staging: 8x cohLoad4 -> regs -> b128 LDS writes
    {
      float4 v1r[4], v2r[4];
      #pragma unroll
      for (int i = 0; i < 4; ++i) {
        const int r = i * 4 + rq;
        v1r[i] = cohLoad4(p.stack + ((size_t)(b0 + r) * SROWS + sp1t[step][r]) * 1024 + kb);
        v2r[i] = cohLoad4(p.stack + ((size_t)(b0 + r) * SROWS + sp2t[step][r]) * 1024 + kb);
      }
      #pragma unroll
      for (int i = 0; i < 4; ++i) {
        const int r = i * 4 + rq;
        *(float4*)&opAll[r][512 + kb]  = v1r[i];
        *(float4*)&opAll[r][1024 + kb] = v2r[i];
      }
    }
    if (anyred && t < 256) {
      const int n = t & 15, bl = t >> 4, na = nc0 + n;
      clv = cohLoad(p.stack + ((size_t)(b0 + bl) * SROWS + sp1t[step][bl]) * 1024 + 512 + na);
      crv = cohLoad(p.stack + ((size_t)(b0 + bl) * SROWS + sp2t[step][bl]) * 1024 + 512 + na);
    }
    if (!anyred) drainvm();            // shift stores -> IC before arrival
    __syncthreads();
    if (!anyred) barA_arrive(blkA, gAn, cg);   // EARLY: row already written

    // ---- compute: tree on t<256 || tracking on t>=256
    if (t < 256) {
      if (anyred) {
        const int bth = t & 3, cth = (t >> 2) & 15, kth = t >> 6;
        const int g = cth >> 2;
        const float* Um = (kth < 2) ? p.Ul[g] : p.Ur[g];
        const int koff = (kth & 1) * 256;
        const int nb = nc0 + (cth & 3) * 4;
        const float* w0 = Um + (size_t)(nb    ) * 512 + koff;
        const float* w1 = Um + (size_t)(nb + 1) * 512 + koff;
        const float* w2 = Um + (size_t)(nb + 2) * 512 + koff;
        const float* w3 = Um + (size_t)(nb + 3) * 512 + koff;
        const int ob = ((kth < 2) ? 512 : 1024) + koff;
        float acc[4][4];
        #pragma unroll
        for (int i = 0; i < 4; ++i)
          #pragma unroll
          for (int j = 0; j < 4; ++j) acc[i][j] = 0.0f;
        #pragma unroll 2
        for (int k4 = 0; k4 < 64; ++k4) {
          const int kk = k4 * 4;
          float4 wv0 = *(const float4*)(w0 + kk);
          float4 wv1 = *(const float4*)(w1 + kk);
          float4 wv2 = *(const float4*)(w2 + kk);
          float4 wv3 = *(const float4*)(w3 + kk);
          #pragma unroll
          for (int bi = 0; bi < 4; ++bi) {
            float4 ov = *(const float4*)&opAll[bi * 4 + bth][ob + kk];
            acc[0][bi] += wv0.x*ov.x + wv0.y*ov.y + wv0.z*ov.z + wv0.w*ov.w;
            acc[1][bi] += wv1.x*ov.x + wv1.y*ov.y + wv1.z*ov.z + wv1.w*ov.w;
            acc[2][bi] += wv2.x*ov.x + wv2.y*ov.y + wv2.z*ov.z + wv2.w*ov.w;
            acc[3][bi] += wv3.x*ov.x + wv3.y*ov.y + wv3.z*ov.z + wv3.w*ov.w;
          }
        }
        const int cc0 = cth * 4;
        #pragma unroll
        for (int ci = 0; ci < 4; ++ci)
          #pragma unroll
          for (int bi = 0; bi < 4; ++bi)
            accS[kth][cc0 + ci][bi * 4 + bth] = acc[ci][bi];
      }
    } else {
      const int tt = t - 256;
      const int q = tt >> 6;
      const int lane = tt & 63;
      const int o = lane >> 3, kth = lane & 7;
      const int r0 = q * 4;
      const float* wrow = p.tWih + (size_t)(o0 + o) * 1536;
      const float* whh  = p.tWhh + (size_t)(o0 + o) * 64;
      const int k0 = kth * 200;
      float tacc[4] = {0.f, 0.f, 0.f, 0.f};
      #pragma unroll 2
      for (int kf = 0; kf < 50; ++kf) {
        const int k = k0 + kf * 4;
        const float* wsrc = (k < 1536) ? (wrow + k) : (whh + (k - 1536));
        float4 wv = *(const float4*)wsrc;
        #pragma unroll
        for (int ri = 0; ri < 4; ++ri) {
          const int r = r0 + ri;
          const float* os = (k < 1536) ? &opAll[r][k] : &th2s[r][k - 1536];
          float4 ov = *(const float4*)os;
          tacc[ri] += wv.x*ov.x + wv.y*ov.y + wv.z*ov.z + wv.w*ov.w;
        }
      }
      #pragma unroll
      for (int ri = 0; ri < 4; ++ri) {
        float v = tacc[ri];
        v += __shfl_xor(v, 1);
        v += __shfl_xor(v, 2);
        v += __shfl_xor(v, 4);
        tacc[ri] = v;
      }
      if (kth == 0) {
        #pragma unroll
        for (int ri = 0; ri < 4; ++ri)
          cohStore(p.tg + (size_t)(b0 + r0 + ri) * 256 + o0 + o, tacc[ri]);
      }
      drainvm();                        // wave-level: tg stores -> IC
      if (lane == 0) barB_arrive_lane(blkB, gB, cg);   // EARLY arrival
    }
    __syncthreads();

    // ---- fill barrier-B latency: reduce accS over kth
    if (anyred) {
      #pragma unroll
      for (int rep = 0; rep < 2; ++rep) {
        const int it = t + rep * 512;
        const int cc = it >> 4, bl = it & 15;
        accR[cc][bl] = accS[0][cc][bl] + accS[1][cc][bl]
                     + accS[2][cc][bl] + accS[3][cc][bl];
      }
    }
    bar_wait(blkB, gB);                // tg of whole set now visible

    // ---- tracking LSTM elementwise (16 b x 64 j; 8 tg loads up-front)
    {
      float gi[2], gf[2], gg[2], go[2];
      int bbp[2], jjp[2];
      #pragma unroll
      for (int rep = 0; rep < 2; ++rep) {
        const int it = t + rep * 512;
        bbp[rep] = it >> 6; jjp[rep] = it & 63;
        const float* tgb = p.tg + (size_t)(b0 + bbp[rep]) * 256;
        gi[rep] = cohLoad(tgb + jjp[rep]);
        gf[rep] = cohLoad(tgb + 64 + jjp[rep]);
        gg[rep] = cohLoad(tgb + 128 + jjp[rep]);
        go[rep] = cohLoad(tgb + 192 + jjp[rep]);
      }
      #pragma unroll
      for (int rep = 0; rep < 2; ++rep) {
        const int b = bbp[rep], j = jjp[rep];
        float c2 = sigm(gf[rep] + tbsum[64 + j]) * tc2s[b][j]
                 + sigm(gi[rep] + tbsum[j]) * tanh_f(gg[rep] + tbsum[128 + j]);
        float h2 = sigm(go[rep] + tbsum[192 + j]) * tanh_f(c2);
        tc2s[b][j] = c2;
        th2s[b][j] = h2;
      }
    }
    if (anyred) {
      __syncthreads();
      // x@W: 64 cc x 16 b, K=64
      #pragma unroll
      for (int rep = 0; rep < 2; ++rep) {
        const int it = t + rep * 512;
        const int cc = it >> 4, bl = it & 15;
        const float* wr = p.Wx[cc >> 4] + (size_t)(nc0 + (cc & 15)) * 64;
        float x = 0.f;
        #pragma unroll 4
        for (int j4 = 0; j4 < 64; j4 += 4) {
          float4 wv = *(const float4*)(wr + j4);
          float4 xv = *(const float4*)&th2s[bl][j4];
          x += wv.x*xv.x + wv.y*xv.y + wv.z*xv.z + wv.w*xv.w;
        }
        xS[cc][bl] = x;
      }
      __syncthreads();
      // gates + stack row write
      if (t < 256) {
        const int n = t & 15, bl = t >> 4, na = nc0 + n;
        float h, c;
        if (redt[step][bl]) {
          float pre[4];
          #pragma unroll
          for (int g = 0; g < 4; ++g) {
            const int cc = g * 16 + n;
            pre[g] = accR[cc][bl] + xS[cc][bl] + biasS[g][n];
          }
          float iv = sigm(pre[0]), ov = sigm(pre[1]);
          float fv = sigm(pre[2]), uv = tanh_f(pre[3]);
          c = iv * uv + fv * (clv + crv);
          h = ov * tanh_f(c);
        } else { h = bhv; c = bcv; }
        float* sr = p.stack + ((size_t)(b0 + bl) * SROWS + step) * 1024;
        cohStore(sr + na, h);
        cohStore(sr + 512 + na, c);
        if (step == TT) p.out[(size_t)(b0 + bl) * 512 + na] = h;
        drainvm();
      }
      __syncthreads();
      barA_arrive(blkA, gAn, cg);
    }
    genA = gAn;
  }
}

extern "C" void kernel_launch(void* const* d_in, const int* in_sizes, int n_in,
                              void* d_out, int out_size, void* d_ws, size_t ws_size,
                              hipStream_t stream) {
  Params p;
  p.seq   = (const float*)d_in[0];
  p.trans = (const int*)d_in[1];
  p.Wx[0] = (const float*)d_in[2];   // W_i
  p.Wx[1] = (const float*)d_in[4];   // W_o
  p.Wx[2] = (const float*)d_in[4];   // W_o  (ref bug: f-gate uses W_o)
  p.Wx[3] = (const float*)d_in[5];   // W_u
  p.Ul[0] = (const float*)d_in[6];  p.Ur[0] = (const float*)d_in[7];    // i
  p.Ul[1] = (const float*)d_in[10]; p.Ur[1] = (const float*)d_in[11];   // o
  p.Ul[2] = (const float*)d_in[8];  p.Ur[2] = (const float*)d_in[9];    // f
  p.Ul[3] = (const float*)d_in[12]; p.Ur[3] = (const float*)d_in[13];   // u
  p.bias[0] = (const float*)d_in[14];  // b_i
  p.bias[1] = (const float*)d_in[16];  // b_o
  p.bias[2] = (const float*)d_in[15];  // b_f
  p.bias[3] = (const float*)d_in[17];  // b_u
  p.tWih = (const float*)d_in[18];
  p.tWhh = (const float*)d_in[19];
  p.tbih = (const float*)d_in[20];
  p.tbhh = (const float*)d_in[21];
  p.th0  = (const float*)d_in[22];
  p.tc0  = (const float*)d_in[23];

  float* ws = (float*)d_ws;
  size_t off = 0;
  p.stack = ws + off; off += (size_t)NB * SROWS * 1024;  // 33.5 MB
  p.tg    = ws + off; off += (size_t)NB * 256;           // 128 KB
  unsigned* barmem = (unsigned*)(ws + off); off += 4096; // 16 KB
  if (off * sizeof(float) > ws_size) return;
  p.bm  = barmem;
  p.out = (float*)d_out;

  hipMemsetAsync(barmem, 0, 4096 * sizeof(unsigned), stream);

  void* args[] = { &p };
  hipError_t e = hipLaunchCooperativeKernel((void*)spinn_kernel, dim3(NWG), dim3(NTH),
                                            args, 0, stream);
  if (e != hipSuccess) {
    (void)hipGetLastError();
    spinn_kernel<<<dim3(NWG), dim3(NTH), 0, stream>>>(p);
  }
}